// Round 11
// baseline (2361.056 us; speedup 1.0000x reference)
//
#include <hip/hip_runtime.h>
#include <stdint.h>

// Problem constants: B=32, T=512, I=1024, H=1024, 4H=4096, M=B*T=16384.
#define BB 32
#define TT 512
#define KK 1024
#define GG 4096
#define MM 16384
#define NSLICE 32     // H-col slices (32 h-cols each)
#define SCAN_WGS 64   // 2 batch-groups x 32 slices; 512 threads each
#define HPAD 1032     // LDS h row stride in shorts (1024 + 8 pad)

typedef __attribute__((ext_vector_type(8))) short short8;
typedef __attribute__((ext_vector_type(4))) short short4v;
typedef __attribute__((ext_vector_type(4))) float f32x4;
typedef unsigned long long u64;

__device__ inline short f2bf(float f) {
  union { float f; unsigned u; } v; v.f = f;
  unsigned r = (v.u + 0x7FFFu + ((v.u >> 16) & 1u)) >> 16;  // RNE
  return (short)(unsigned short)r;
}
__device__ inline float bf2f(short s) {
  union { unsigned u; float f; } v; v.u = ((unsigned)(unsigned short)s) << 16;
  return v.f;
}
__device__ inline float sigmoid_f(float x) { return 1.0f / (1.0f + __expf(-x)); }
__device__ inline float tanh_f(float x)    { return 1.0f - 2.0f / (__expf(2.0f * x) + 1.0f); }

// ---------------- prep kernels ----------------

__global__ void zero_ws(unsigned* __restrict__ p, int n) {
  int i = blockIdx.x * 256 + threadIdx.x;
  if (i < n) p[i] = 0u;
}

// float -> bf16, 4 elements/thread
__global__ void cvt_bf16(const float* __restrict__ in, short* __restrict__ out, int n4) {
  int i = blockIdx.x * 256 + threadIdx.x;
  if (i >= n4) return;
  f32x4 v = *(const f32x4*)(in + (size_t)i * 4);
  short4v o;
  o.x = f2bf(v.x); o.y = f2bf(v.y); o.z = f2bf(v.z); o.w = f2bf(v.w);
  *(short4v*)(out + (size_t)i * 4) = o;
}

// Pack W_hh into per-wave MFMA-A-fragment order (z^T = W_hh * h^T form).
// Wave nt (0..7) covers within-tile z-cols c = 4*j + g  (j = h-col sub 0..3,
// g = gate 0..3):  W_hh row = g*1024 + slice*32 + nt*4 + j.
// A-frag (16x16x32): A[m = lane&15 = c][k = s*32 + (lane>>4)*8 + jj]
// wpack[((slice*8+nt)*32 + s)*512 + lane*8 + jj]
__global__ void pack_whh(const float* __restrict__ Whh, short* __restrict__ wpack) {
  int idx = blockIdx.x * 256 + threadIdx.x;          // < 32*8*32*64 = 524288
  if (idx >= NSLICE * 8 * 32 * 64) return;
  int lane  = idx & 63;
  int s     = (idx >> 6) & 31;
  int nt    = (idx >> 11) & 7;
  int slice = idx >> 14;
  int c     = lane & 15;
  int row   = (c & 3) * 1024 + slice * 32 + nt * 4 + (c >> 2);
  int k     = s * 32 + (lane >> 4) * 8;
  const float* src = Whh + (size_t)row * KK + k;
  short8 v;
#pragma unroll
  for (int j = 0; j < 8; ++j) v[j] = f2bf(src[j]);
  *(short8*)(wpack + ((size_t)((slice * 8 + nt) * 32 + s)) * 512 + lane * 8) = v;
}

// ---------------- phase 1: xW = x @ W_ih^T + b ----------------
template <bool XWF32>
__global__ __launch_bounds__(256) void gemm_xw(const short* __restrict__ A,
                                               const short* __restrict__ Bw,
                                               const float* __restrict__ bias,
                                               void* __restrict__ Cv) {
  __shared__ short As[128 * 32];
  __shared__ short Bs[128 * 32];
  const int tid = threadIdx.x;
  const int m0 = blockIdx.y * 128;
  const int n0 = blockIdx.x * 128;
  const int lane = tid & 63, wv = tid >> 6;
  const int wm = (wv >> 1) * 64, wn = (wv & 1) * 64;
  const int fr = lane & 15;
  const int fq = (lane >> 4) * 8;
  const int quad = lane >> 4;
  f32x4 acc[4][4];
#pragma unroll
  for (int i = 0; i < 4; ++i)
#pragma unroll
    for (int j = 0; j < 4; ++j) acc[i][j] = (f32x4){0.f, 0.f, 0.f, 0.f};

  const int sr = tid >> 2;
  const int sc = (tid & 3) * 8;
  const short* Ag = A + (size_t)(m0 + sr) * KK + sc;
  const short* Bg = Bw + (size_t)(n0 + sr) * KK + sc;

  for (int kb = 0; kb < KK; kb += 32) {
    short8 a0 = *(const short8*)(Ag + kb);
    short8 a1 = *(const short8*)(Ag + (size_t)64 * KK + kb);
    short8 b0 = *(const short8*)(Bg + kb);
    short8 b1 = *(const short8*)(Bg + (size_t)64 * KK + kb);
    __syncthreads();
    *(short8*)&As[sr * 32 + sc] = a0;
    *(short8*)&As[(64 + sr) * 32 + sc] = a1;
    *(short8*)&Bs[sr * 32 + sc] = b0;
    *(short8*)&Bs[(64 + sr) * 32 + sc] = b1;
    __syncthreads();
    short8 af[4], bf[4];
#pragma unroll
    for (int i = 0; i < 4; ++i) {
      af[i] = *(const short8*)&As[(wm + i * 16 + fr) * 32 + fq];
      bf[i] = *(const short8*)&Bs[(wn + i * 16 + fr) * 32 + fq];
    }
#pragma unroll
    for (int i = 0; i < 4; ++i)
#pragma unroll
      for (int j = 0; j < 4; ++j)
        acc[i][j] = __builtin_amdgcn_mfma_f32_16x16x32_bf16(af[i], bf[j], acc[i][j], 0, 0, 0);
  }
#pragma unroll
  for (int i = 0; i < 4; ++i) {
    int mrow = m0 + wm + i * 16 + quad * 4;
#pragma unroll
    for (int j = 0; j < 4; ++j) {
      int ncol = n0 + wn + j * 16 + fr;
      float bv = bias[ncol];
#pragma unroll
      for (int r = 0; r < 4; ++r) {
        float v = acc[i][j][r] + bv;
        size_t idx = (size_t)(mrow + r) * GG + ncol;
        if (XWF32) ((float*)Cv)[idx] = v;
        else       ((short*)Cv)[idx] = f2bf(v);
      }
    }
  }
}

// ---------------- persistent LSTM scan: group-local flag dataflow -----------
// 64 WGs x 512 threads. WG = (group = wg>>5, slice = wg&31): batch rows
// group*16..+15, h-cols slice*32..+31 (x4 gates). The two groups are fully
// independent recurrence chains (disjoint h slabs, flags, outputs).
//
// ROUND-8 FIX (counter-driven): __launch_bounds__(512, 2).
//   Round 7 kept VGPR_Count at 88 despite loop-top W loads: default
//   launch_bounds targets >2 waves/SIMD occupancy, but this kernel runs
//   exactly 1 WG/CU (64 WGs on 256 CUs). At 88 VGPRs the compiler split
//   wreg[32] (needs 128 VGPRs) into serialized L2 load batches INSIDE the
//   MFMA phase (~3 x ~300cy on the critical path after S0). With the
//   2-waves/EU bound (cap 256 VGPR), W is preloaded ONCE before the loop
//   and stays resident for all 512 steps. xW(t+1) prefetch hoisted to loop
//   top so its latency sits fully under the poll.
//
// Sync per step: [xW(t+1) prefetch issued] -> wave0 polls 32 padded flags
// (64B slots, 1 line/lane, s_sleep between rounds) -> S_a -> slab load
// (each wave its 4 KB once) -> LDS stage -> S0 -> MFMA+gates -> h store
// (sc1) -> S2 (vmcnt(0) drain) -> tid0 flag store -> out store.
// Freshness: flags[Q]=t implies Q passed S2(t-1) implies Q's h(t) stores
//   acked at LLC. Overrun: flags[Q]=t implies Q finished reading h(t-1)
//   (staged before S0(t-1) < S2(t-1)), so our h(t+1) store into the same
//   buffer as h(t-1) is safe after poll>=t. 2-buffer parity suffices.
//
// MFMA computes z^T = W_hh * h^T: A = W frags (z-cols packed c=4j+g),
// B = h rows from LDS. C/D layout gives each lane acc[r] = gate r for one
// (b = lane&15, j = quad) -> gates fuse per-lane, no partials pass.
template <bool XWF32>
__global__ __launch_bounds__(512, 2) void lstm_scan(const void* __restrict__ xWv,
                                                    const short* __restrict__ wpack,
                                                    short* __restrict__ hbuf,
                                                    unsigned* __restrict__ flags,
                                                    float* __restrict__ out) {
  const int wg = blockIdx.x;
  const int group = wg >> 5;            // 0..1
  const int slice = wg & 31;            // 0..31
  const int tid = threadIdx.x;
  const int lane = tid & 63;
  const int wv = tid >> 6;              // wave 0..7 (also n-tile / col-slice)
  const int quad = lane >> 4;           // j within tile (0..3)
  const int bloc = lane & 15;           // batch row within group
  const int bglob = group * 16 + bloc;
  const int jglob = slice * 32 + wv * 4 + quad;

  // ---- W_hh A-fragments: preload ONCE, resident for all 512 steps ----
  short8 wreg[32];
  {
    const short* wp = wpack + ((size_t)((slice * 8 + wv) * 32)) * 512 + lane * 8;
#pragma unroll
    for (int s = 0; s < 32; ++s) wreg[s] = *(const short8*)(wp + (size_t)s * 512);
  }

  __shared__ short hstage[16 * HPAD];   // single buffer, ~33 KB

  float c_reg = 0.f;
  const float* xwf = (const float*)xWv;
  const short* xwh = (const short*)xWv;

  // xW prefetch for t=0 (4 gate values per lane)
  float xwv_[4];
  {
    size_t xb = ((size_t)bglob * TT) * GG + jglob;
#pragma unroll
    for (int g = 0; g < 4; ++g)
      xwv_[g] = XWF32 ? xwf[xb + (size_t)g * 1024] : bf2f(xwh[xb + (size_t)g * 1024]);
  }

  unsigned* gflags = flags + (size_t)group * 32 * 16;   // 64B-padded slots

#pragma unroll 1
  for (int t = 0; t < TT; ++t) {
    const int buf = t & 1;
    // ---- issue xW(t+1) prefetch first: latency hides under the poll ----
    float xwn[4] = {0.f, 0.f, 0.f, 0.f};
    if (t + 1 < TT) {
      size_t xb = ((size_t)bglob * TT + t + 1) * GG + jglob;
#pragma unroll
      for (int g = 0; g < 4; ++g)
        xwn[g] = XWF32 ? xwf[xb + (size_t)g * 1024] : bf2f(xwh[xb + (size_t)g * 1024]);
    }

    // ---- wave 0 polls 32 padded group flags (1 line/lane) ----
    if (wv == 0 && t > 0) {
      const unsigned need = (unsigned)t;
      while (true) {
        unsigned f = need;
        if (lane < 32)
          f = __hip_atomic_load(&gflags[(size_t)lane * 16], __ATOMIC_RELAXED,
                                __HIP_MEMORY_SCOPE_AGENT);
        if (__all((int)(f >= need))) break;
        __builtin_amdgcn_s_sleep(1);
      }
    }
    __syncthreads();  // S_a: freshness certified for all waves

    // ---- bulk-load wave's slab slice ONCE: cols wv*128..+127, 16 rows ----
    const u64* sb = (const u64*)(hbuf + ((size_t)(buf * 2 + group)) * 16384);
    u64 hv[8];
#pragma unroll
    for (int k = 0; k < 8; ++k) {
      int pos = k * 64 + lane;            // 0..511 within wave portion
      int row = pos >> 5, cu = pos & 31;  // 16 rows x 32 u64
      hv[k] = __hip_atomic_load(&sb[row * 256 + wv * 32 + cu], __ATOMIC_RELAXED,
                                __HIP_MEMORY_SCOPE_AGENT);
    }
    // ---- stage slice to LDS ----
#pragma unroll
    for (int k = 0; k < 8; ++k) {
      int pos = k * 64 + lane;
      int row = pos >> 5, cu = pos & 31;
      *(u64*)&hstage[row * HPAD + (wv * 32 + cu) * 4] = hv[k];
    }
    __syncthreads();  // S0: hstage visible

    // ---- MFMA: z^T tile; A = W regs (resident), B = h rows from LDS ----
    f32x4 acc0 = (f32x4){0.f, 0.f, 0.f, 0.f};
    f32x4 acc1 = (f32x4){0.f, 0.f, 0.f, 0.f};
    const short* hrow = hstage + bloc * HPAD + quad * 8;
#pragma unroll
    for (int s = 0; s < 32; s += 2) {
      short8 b0 = *(const short8*)(hrow + s * 32);
      short8 b1 = *(const short8*)(hrow + (s + 1) * 32);
      acc0 = __builtin_amdgcn_mfma_f32_16x16x32_bf16(wreg[s], b0, acc0, 0, 0, 0);
      acc1 = __builtin_amdgcn_mfma_f32_16x16x32_bf16(wreg[s + 1], b1, acc1, 0, 0, 0);
    }

    // ---- gates: acc[r] = gate r for (bglob, jglob) ----
    float i_ = sigmoid_f(acc0[0] + acc1[0] + xwv_[0]);
    float f_ = sigmoid_f(acc0[1] + acc1[1] + xwv_[1]);
    float g_ = tanh_f(acc0[2] + acc1[2] + xwv_[2]);
    float o_ = sigmoid_f(acc0[3] + acc1[3] + xwv_[3]);
    c_reg = f_ * c_reg + i_ * g_;
    float h_ = o_ * tanh_f(c_reg);

    // ---- h(t+1) store (sc1): pack 2 bf16 via shfl ----
    unsigned hb16 = (unsigned)(unsigned short)f2bf(h_);
    unsigned oth = __shfl_xor(hb16, 16, 64);   // partner quad^1 -> jglob^1
    if (!(quad & 1)) {
      unsigned packed = hb16 | (oth << 16);    // cols jglob, jglob+1
      size_t so = ((size_t)((buf ^ 1) * 2 + group)) * 16384 +
                  (size_t)bloc * 1024 + jglob;
      __hip_atomic_store((unsigned*)(hbuf + so), packed, __ATOMIC_RELAXED,
                         __HIP_MEMORY_SCOPE_AGENT);
    }

    __syncthreads();  // S2: per-wave vmcnt(0) drain -> h(t+1) acked at LLC
    if (tid == 0)
      __hip_atomic_store(&flags[(size_t)wg * 16], (unsigned)(t + 1),
                         __ATOMIC_RELAXED, __HIP_MEMORY_SCOPE_AGENT);

    // out store AFTER flag publish: its ack drains at next step's S2,
    // overlapped with the poll instead of delaying this flag.
    out[((size_t)bglob * TT + t) * 1024 + jglob] = h_;

#pragma unroll
    for (int g = 0; g < 4; ++g) xwv_[g] = xwn[g];
  }
}

// ---------------- launch ----------------

extern "C" void kernel_launch(void* const* d_in, const int* in_sizes, int n_in,
                              void* d_out, int out_size, void* d_ws, size_t ws_size,
                              hipStream_t stream) {
  const float* x    = (const float*)d_in[0];   // [32,512,1024]
  const float* Wih  = (const float*)d_in[1];   // [4096,1024]
  const float* Whh  = (const float*)d_in[2];   // [4096,1024]
  const float* bias = (const float*)d_in[3];   // [4096]
  float* out = (float*)d_out;

  char* ws = (char*)d_ws;
  // ws layout (bytes)
  const size_t o_xbf   = 0;                         // 33,554,432
  const size_t o_wih   = 33554432;                  //  8,388,608
  const size_t o_wpack = 41943040;                  //  8,388,608
  const size_t o_hbuf  = 50331648;                  //    131,072 (bf16[2][2][16][1024])
  const size_t o_flag  = 50462720;                  //      4,096 (u32[64] padded x16)
  const size_t o_xw    = 50466816;                  // 256 MB (f32) or 128 MB (bf16)
  const bool xwf32 = ws_size >= (o_xw + (size_t)MM * GG * 4);

  short* xbf      = (short*)(ws + o_xbf);
  short* wihbf    = (short*)(ws + o_wih);
  short* wpack    = (short*)(ws + o_wpack);
  short* hbuf     = (short*)(ws + o_hbuf);
  unsigned* flags = (unsigned*)(ws + o_flag);
  void* xw        = (void*)(ws + o_xw);

  // zero h double-buffer (h(0)=0) + padded flags (0 = "h(0) ready")
  zero_ws<<<132, 256, 0, stream>>>((unsigned*)(ws + o_hbuf), 33792);
  // x -> bf16 (16,777,216 elems)
  cvt_bf16<<<16384, 256, 0, stream>>>(x, xbf, 4194304);
  // W_ih -> bf16 (4,194,304 elems)
  cvt_bf16<<<4096, 256, 0, stream>>>(Wih, wihbf, 1048576);
  // W_hh -> packed MFMA-A fragments (z^T form)
  pack_whh<<<2048, 256, 0, stream>>>(Whh, wpack);

  dim3 g1(GG / 128, MM / 128);  // (32, 128)
  if (xwf32) gemm_xw<true ><<<g1, 256, 0, stream>>>(xbf, wihbf, bias, xw);
  else       gemm_xw<false><<<g1, 256, 0, stream>>>(xbf, wihbf, bias, xw);

  if (xwf32) lstm_scan<true ><<<SCAN_WGS, 512, 0, stream>>>(xw, wpack, hbuf, flags, out);
  else       lstm_scan<false><<<SCAN_WGS, 512, 0, stream>>>(xw, wpack, hbuf, flags, out);
}

// Round 12
// 2306.207 us; speedup vs baseline: 1.0238x; 1.0238x over previous
//
#include <hip/hip_runtime.h>
#include <stdint.h>

// Problem constants: B=32, T=512, I=1024, H=1024, 4H=4096, M=B*T=16384.
#define BB 32
#define TT 512
#define KK 1024
#define GG 4096
#define MM 16384
#define NSLICE 32     // H-col slices (32 h-cols each)
#define SCAN_WGS 64   // 2 batch-groups x 32 slices; 512 threads each
#define HPAD 1032     // LDS h row stride in shorts (1024 + 8 pad)

typedef __attribute__((ext_vector_type(8))) short short8;
typedef __attribute__((ext_vector_type(4))) short short4v;
typedef __attribute__((ext_vector_type(4))) float f32x4;
typedef unsigned long long u64;

__device__ inline short f2bf(float f) {
  union { float f; unsigned u; } v; v.f = f;
  unsigned r = (v.u + 0x7FFFu + ((v.u >> 16) & 1u)) >> 16;  // RNE
  return (short)(unsigned short)r;
}
__device__ inline float bf2f(short s) {
  union { unsigned u; float f; } v; v.u = ((unsigned)(unsigned short)s) << 16;
  return v.f;
}
__device__ inline float sigmoid_f(float x) { return 1.0f / (1.0f + __expf(-x)); }
__device__ inline float tanh_f(float x)    { return 1.0f - 2.0f / (__expf(2.0f * x) + 1.0f); }

// ---------------- prep kernels ----------------

__global__ void zero_ws(unsigned* __restrict__ p, int n) {
  int i = blockIdx.x * 256 + threadIdx.x;
  if (i < n) p[i] = 0u;
}

// float -> bf16, 4 elements/thread
__global__ void cvt_bf16(const float* __restrict__ in, short* __restrict__ out, int n4) {
  int i = blockIdx.x * 256 + threadIdx.x;
  if (i >= n4) return;
  f32x4 v = *(const f32x4*)(in + (size_t)i * 4);
  short4v o;
  o.x = f2bf(v.x); o.y = f2bf(v.y); o.z = f2bf(v.z); o.w = f2bf(v.w);
  *(short4v*)(out + (size_t)i * 4) = o;
}

// Pack W_hh into per-wave MFMA-A-fragment order (z^T = W_hh * h^T form).
// Wave nt (0..7) covers within-tile z-cols c = 4*j + g  (j = h-col sub 0..3,
// g = gate 0..3):  W_hh row = g*1024 + slice*32 + nt*4 + j.
// A-frag (16x16x32): A[m = lane&15 = c][k = s*32 + (lane>>4)*8 + jj]
// wpack[((slice*8+nt)*32 + s)*512 + lane*8 + jj]
__global__ void pack_whh(const float* __restrict__ Whh, short* __restrict__ wpack) {
  int idx = blockIdx.x * 256 + threadIdx.x;          // < 32*8*32*64 = 524288
  if (idx >= NSLICE * 8 * 32 * 64) return;
  int lane  = idx & 63;
  int s     = (idx >> 6) & 31;
  int nt    = (idx >> 11) & 7;
  int slice = idx >> 14;
  int c     = lane & 15;
  int row   = (c & 3) * 1024 + slice * 32 + nt * 4 + (c >> 2);
  int k     = s * 32 + (lane >> 4) * 8;
  const float* src = Whh + (size_t)row * KK + k;
  short8 v;
#pragma unroll
  for (int j = 0; j < 8; ++j) v[j] = f2bf(src[j]);
  *(short8*)(wpack + ((size_t)((slice * 8 + nt) * 32 + s)) * 512 + lane * 8) = v;
}

// ---------------- phase 1: xW = x @ W_ih^T + b ----------------
template <bool XWF32>
__global__ __launch_bounds__(256) void gemm_xw(const short* __restrict__ A,
                                               const short* __restrict__ Bw,
                                               const float* __restrict__ bias,
                                               void* __restrict__ Cv) {
  __shared__ short As[128 * 32];
  __shared__ short Bs[128 * 32];
  const int tid = threadIdx.x;
  const int m0 = blockIdx.y * 128;
  const int n0 = blockIdx.x * 128;
  const int lane = tid & 63, wv = tid >> 6;
  const int wm = (wv >> 1) * 64, wn = (wv & 1) * 64;
  const int fr = lane & 15;
  const int fq = (lane >> 4) * 8;
  const int quad = lane >> 4;
  f32x4 acc[4][4];
#pragma unroll
  for (int i = 0; i < 4; ++i)
#pragma unroll
    for (int j = 0; j < 4; ++j) acc[i][j] = (f32x4){0.f, 0.f, 0.f, 0.f};

  const int sr = tid >> 2;
  const int sc = (tid & 3) * 8;
  const short* Ag = A + (size_t)(m0 + sr) * KK + sc;
  const short* Bg = Bw + (size_t)(n0 + sr) * KK + sc;

  for (int kb = 0; kb < KK; kb += 32) {
    short8 a0 = *(const short8*)(Ag + kb);
    short8 a1 = *(const short8*)(Ag + (size_t)64 * KK + kb);
    short8 b0 = *(const short8*)(Bg + kb);
    short8 b1 = *(const short8*)(Bg + (size_t)64 * KK + kb);
    __syncthreads();
    *(short8*)&As[sr * 32 + sc] = a0;
    *(short8*)&As[(64 + sr) * 32 + sc] = a1;
    *(short8*)&Bs[sr * 32 + sc] = b0;
    *(short8*)&Bs[(64 + sr) * 32 + sc] = b1;
    __syncthreads();
    short8 af[4], bf[4];
#pragma unroll
    for (int i = 0; i < 4; ++i) {
      af[i] = *(const short8*)&As[(wm + i * 16 + fr) * 32 + fq];
      bf[i] = *(const short8*)&Bs[(wn + i * 16 + fr) * 32 + fq];
    }
#pragma unroll
    for (int i = 0; i < 4; ++i)
#pragma unroll
      for (int j = 0; j < 4; ++j)
        acc[i][j] = __builtin_amdgcn_mfma_f32_16x16x32_bf16(af[i], bf[j], acc[i][j], 0, 0, 0);
  }
#pragma unroll
  for (int i = 0; i < 4; ++i) {
    int mrow = m0 + wm + i * 16 + quad * 4;
#pragma unroll
    for (int j = 0; j < 4; ++j) {
      int ncol = n0 + wn + j * 16 + fr;
      float bv = bias[ncol];
#pragma unroll
      for (int r = 0; r < 4; ++r) {
        float v = acc[i][j][r] + bv;
        size_t idx = (size_t)(mrow + r) * GG + ncol;
        if (XWF32) ((float*)Cv)[idx] = v;
        else       ((short*)Cv)[idx] = f2bf(v);
      }
    }
  }
}

// ---------------- persistent LSTM scan: group-local flag dataflow -----------
// 64 WGs x 512 threads. WG = (group = wg>>5, slice = wg&31): batch rows
// group*16..+15, h-cols slice*32..+31 (x4 gates). The two groups are fully
// independent recurrence chains (disjoint h slabs, flags, outputs).
//
// ROUND-12 FIX (counter-driven): opaque-value pin for W residency.
//   Round 11 showed __launch_bounds__(512,2) alone does NOT make the
//   compiler keep wreg[32] (128 VGPRs) resident: VGPR_Count stayed 88 -
//   the allocator rematerializes the loop-invariant wpack loads inside the
//   MFMA phase every step (serialized L2 batches on the critical path after
//   S0). Fix: after the one-time preload, `asm volatile("" : "+v"(w))` on
//   each fragment makes the values opaque (cannot be re-derived from the
//   load), forcing allocation across the t-loop. Budget: 128 (W) + ~88
//   (working set) = ~216 < 256 cap from (512,2) -> no spill.
//   Falsifiable: VGPR_Count must jump to ~200-230.
//
// Sync per step: [xW(t+1) prefetch issued] -> wave0 polls 32 padded flags
// (64B slots, 1 line/lane, s_sleep between rounds) -> S_a -> slab load
// (each wave its 4 KB once) -> LDS stage -> S0 -> MFMA+gates -> h store
// (sc1) -> S2 (vmcnt(0) drain) -> tid0 flag store -> out store.
// Freshness: flags[Q]=t implies Q passed S2(t-1) implies Q's h(t) stores
//   acked at LLC. Overrun: flags[Q]=t implies Q finished reading h(t-1)
//   (staged before S0(t-1) < S2(t-1)), so our h(t+1) store into the same
//   buffer as h(t-1) is safe after poll>=t. 2-buffer parity suffices.
//
// MFMA computes z^T = W_hh * h^T: A = W frags (z-cols packed c=4j+g),
// B = h rows from LDS. C/D layout gives each lane acc[r] = gate r for one
// (b = lane&15, j = quad) -> gates fuse per-lane, no partials pass.
template <bool XWF32>
__global__ __launch_bounds__(512, 2) void lstm_scan(const void* __restrict__ xWv,
                                                    const short* __restrict__ wpack,
                                                    short* __restrict__ hbuf,
                                                    unsigned* __restrict__ flags,
                                                    float* __restrict__ out) {
  const int wg = blockIdx.x;
  const int group = wg >> 5;            // 0..1
  const int slice = wg & 31;            // 0..31
  const int tid = threadIdx.x;
  const int lane = tid & 63;
  const int wv = tid >> 6;              // wave 0..7 (also n-tile / col-slice)
  const int quad = lane >> 4;           // j within tile (0..3)
  const int bloc = lane & 15;           // batch row within group
  const int bglob = group * 16 + bloc;
  const int jglob = slice * 32 + wv * 4 + quad;

  // ---- W_hh A-fragments: preload ONCE, then PIN (opaque to remat) ----
  short8 wreg[32];
  {
    const short* wp = wpack + ((size_t)((slice * 8 + wv) * 32)) * 512 + lane * 8;
#pragma unroll
    for (int s = 0; s < 32; ++s) wreg[s] = *(const short8*)(wp + (size_t)s * 512);
  }
#pragma unroll
  for (int s = 0; s < 32; ++s) asm volatile("" : "+v"(wreg[s]));

  __shared__ short hstage[16 * HPAD];   // single buffer, ~33 KB

  float c_reg = 0.f;
  const float* xwf = (const float*)xWv;
  const short* xwh = (const short*)xWv;

  // xW prefetch for t=0 (4 gate values per lane)
  float xwv_[4];
  {
    size_t xb = ((size_t)bglob * TT) * GG + jglob;
#pragma unroll
    for (int g = 0; g < 4; ++g)
      xwv_[g] = XWF32 ? xwf[xb + (size_t)g * 1024] : bf2f(xwh[xb + (size_t)g * 1024]);
  }

  unsigned* gflags = flags + (size_t)group * 32 * 16;   // 64B-padded slots

#pragma unroll 1
  for (int t = 0; t < TT; ++t) {
    const int buf = t & 1;
    // ---- issue xW(t+1) prefetch first: latency hides under the poll ----
    float xwn[4] = {0.f, 0.f, 0.f, 0.f};
    if (t + 1 < TT) {
      size_t xb = ((size_t)bglob * TT + t + 1) * GG + jglob;
#pragma unroll
      for (int g = 0; g < 4; ++g)
        xwn[g] = XWF32 ? xwf[xb + (size_t)g * 1024] : bf2f(xwh[xb + (size_t)g * 1024]);
    }

    // ---- wave 0 polls 32 padded group flags (1 line/lane) ----
    if (wv == 0 && t > 0) {
      const unsigned need = (unsigned)t;
      while (true) {
        unsigned f = need;
        if (lane < 32)
          f = __hip_atomic_load(&gflags[(size_t)lane * 16], __ATOMIC_RELAXED,
                                __HIP_MEMORY_SCOPE_AGENT);
        if (__all((int)(f >= need))) break;
        __builtin_amdgcn_s_sleep(1);
      }
    }
    __syncthreads();  // S_a: freshness certified for all waves

    // ---- bulk-load wave's slab slice ONCE: cols wv*128..+127, 16 rows ----
    const u64* sb = (const u64*)(hbuf + ((size_t)(buf * 2 + group)) * 16384);
    u64 hv[8];
#pragma unroll
    for (int k = 0; k < 8; ++k) {
      int pos = k * 64 + lane;            // 0..511 within wave portion
      int row = pos >> 5, cu = pos & 31;  // 16 rows x 32 u64
      hv[k] = __hip_atomic_load(&sb[row * 256 + wv * 32 + cu], __ATOMIC_RELAXED,
                                __HIP_MEMORY_SCOPE_AGENT);
    }
    // ---- stage slice to LDS ----
#pragma unroll
    for (int k = 0; k < 8; ++k) {
      int pos = k * 64 + lane;
      int row = pos >> 5, cu = pos & 31;
      *(u64*)&hstage[row * HPAD + (wv * 32 + cu) * 4] = hv[k];
    }
    __syncthreads();  // S0: hstage visible

    // ---- MFMA: z^T tile; A = W regs (pinned), B = h rows from LDS ----
    f32x4 acc0 = (f32x4){0.f, 0.f, 0.f, 0.f};
    f32x4 acc1 = (f32x4){0.f, 0.f, 0.f, 0.f};
    const short* hrow = hstage + bloc * HPAD + quad * 8;
#pragma unroll
    for (int s = 0; s < 32; s += 2) {
      short8 b0 = *(const short8*)(hrow + s * 32);
      short8 b1 = *(const short8*)(hrow + (s + 1) * 32);
      acc0 = __builtin_amdgcn_mfma_f32_16x16x32_bf16(wreg[s], b0, acc0, 0, 0, 0);
      acc1 = __builtin_amdgcn_mfma_f32_16x16x32_bf16(wreg[s + 1], b1, acc1, 0, 0, 0);
    }

    // ---- gates: acc[r] = gate r for (bglob, jglob) ----
    float i_ = sigmoid_f(acc0[0] + acc1[0] + xwv_[0]);
    float f_ = sigmoid_f(acc0[1] + acc1[1] + xwv_[1]);
    float g_ = tanh_f(acc0[2] + acc1[2] + xwv_[2]);
    float o_ = sigmoid_f(acc0[3] + acc1[3] + xwv_[3]);
    c_reg = f_ * c_reg + i_ * g_;
    float h_ = o_ * tanh_f(c_reg);

    // ---- h(t+1) store (sc1): pack 2 bf16 via shfl ----
    unsigned hb16 = (unsigned)(unsigned short)f2bf(h_);
    unsigned oth = __shfl_xor(hb16, 16, 64);   // partner quad^1 -> jglob^1
    if (!(quad & 1)) {
      unsigned packed = hb16 | (oth << 16);    // cols jglob, jglob+1
      size_t so = ((size_t)((buf ^ 1) * 2 + group)) * 16384 +
                  (size_t)bloc * 1024 + jglob;
      __hip_atomic_store((unsigned*)(hbuf + so), packed, __ATOMIC_RELAXED,
                         __HIP_MEMORY_SCOPE_AGENT);
    }

    __syncthreads();  // S2: per-wave vmcnt(0) drain -> h(t+1) acked at LLC
    if (tid == 0)
      __hip_atomic_store(&flags[(size_t)wg * 16], (unsigned)(t + 1),
                         __ATOMIC_RELAXED, __HIP_MEMORY_SCOPE_AGENT);

    // out store AFTER flag publish: its ack drains at next step's S2,
    // overlapped with the poll instead of delaying this flag.
    out[((size_t)bglob * TT + t) * 1024 + jglob] = h_;

#pragma unroll
    for (int g = 0; g < 4; ++g) xwv_[g] = xwn[g];
  }
}

// ---------------- launch ----------------

extern "C" void kernel_launch(void* const* d_in, const int* in_sizes, int n_in,
                              void* d_out, int out_size, void* d_ws, size_t ws_size,
                              hipStream_t stream) {
  const float* x    = (const float*)d_in[0];   // [32,512,1024]
  const float* Wih  = (const float*)d_in[1];   // [4096,1024]
  const float* Whh  = (const float*)d_in[2];   // [4096,1024]
  const float* bias = (const float*)d_in[3];   // [4096]
  float* out = (float*)d_out;

  char* ws = (char*)d_ws;
  // ws layout (bytes)
  const size_t o_xbf   = 0;                         // 33,554,432
  const size_t o_wih   = 33554432;                  //  8,388,608
  const size_t o_wpack = 41943040;                  //  8,388,608
  const size_t o_hbuf  = 50331648;                  //    131,072 (bf16[2][2][16][1024])
  const size_t o_flag  = 50462720;                  //      4,096 (u32[64] padded x16)
  const size_t o_xw    = 50466816;                  // 256 MB (f32) or 128 MB (bf16)
  const bool xwf32 = ws_size >= (o_xw + (size_t)MM * GG * 4);

  short* xbf      = (short*)(ws + o_xbf);
  short* wihbf    = (short*)(ws + o_wih);
  short* wpack    = (short*)(ws + o_wpack);
  short* hbuf     = (short*)(ws + o_hbuf);
  unsigned* flags = (unsigned*)(ws + o_flag);
  void* xw        = (void*)(ws + o_xw);

  // zero h double-buffer (h(0)=0) + padded flags (0 = "h(0) ready")
  zero_ws<<<132, 256, 0, stream>>>((unsigned*)(ws + o_hbuf), 33792);
  // x -> bf16 (16,777,216 elems)
  cvt_bf16<<<16384, 256, 0, stream>>>(x, xbf, 4194304);
  // W_ih -> bf16 (4,194,304 elems)
  cvt_bf16<<<4096, 256, 0, stream>>>(Wih, wihbf, 1048576);
  // W_hh -> packed MFMA-A fragments (z^T form)
  pack_whh<<<2048, 256, 0, stream>>>(Whh, wpack);

  dim3 g1(GG / 128, MM / 128);  // (32, 128)
  if (xwf32) gemm_xw<true ><<<g1, 256, 0, stream>>>(xbf, wihbf, bias, xw);
  else       gemm_xw<false><<<g1, 256, 0, stream>>>(xbf, wihbf, bias, xw);

  if (xwf32) lstm_scan<true ><<<SCAN_WGS, 512, 0, stream>>>(xw, wpack, hbuf, flags, out);
  else       lstm_scan<false><<<SCAN_WGS, 512, 0, stream>>>(xw, wpack, hbuf, flags, out);
}